// Round 1
// 93.578 us; speedup vs baseline: 1.0306x; 1.0306x over previous
//
#include <hip/hip_runtime.h>
#include <math.h>

// VertexNormals on a fixed S x S structured grid mesh (S=512, BS=8).
//
// 7-point stencil: vertex (r,c) sums unit normals of 6 adjacent triangles,
// masked by border-validity weights, then normalizes.
//
// Round-3 change: vertical register tiling x4. Each thread computes 4
// consecutive rows of one column. The 6-row x 3-col point neighborhood is
// loaded once into registers (18 dwordx3 loads for 4 outputs = 4.5/output
// vs 7/output before), cutting L1 line-transactions per output ~1.45x and
// amortizing address math 4x. HBM floor is ~8 us (25 MB in + 25 MB out);
// the two 41.5 us harness workspace-poison fills per iteration (~83 us)
// are outside our control.

typedef float f3 __attribute__((ext_vector_type(3)));

#define RPT 4  // rows per thread

__device__ __forceinline__ f3 load_pt(const float* __restrict__ base,
                                      int S, int rr, int cc) {
    // 12-byte contiguous, 4-byte aligned -> global_load_dwordx3.
    return *reinterpret_cast<const f3*>(base + (size_t)(rr * S + cc) * 3);
}

// cross(e1,e2), guarded-normalize, accumulate with 0/1 weight w.
__device__ __forceinline__ void accum_face(float w, f3 e1, f3 e2, f3& s) {
    float nx = e1.y * e2.z - e1.z * e2.y;
    float ny = e1.z * e2.x - e1.x * e2.z;
    float nz = e1.x * e2.y - e1.y * e2.x;
    float d  = nx * nx + ny * ny + nz * nz;
    float inv = (d > 0.0f) ? rsqrtf(d) : 0.0f;   // |n| >= ~1e-12 in practice
    inv *= w;
    s.x = fmaf(nx, inv, s.x);
    s.y = fmaf(ny, inv, s.y);
    s.z = fmaf(nz, inv, s.z);
}

__global__ __launch_bounds__(256) void vertex_normals_stencil(
    const float* __restrict__ vrt,   // [BS][S*S][3]
    float*       __restrict__ out,   // [BS][S*S][3]
    int S)
{
    int c  = blockIdx.x * blockDim.x + threadIdx.x;   // column
    int r0 = blockIdx.y * RPT;                         // first row of strip
    int b  = blockIdx.z;                               // batch
    if (c >= S) return;
    int n_verts = S * S;

    int cm = (c > 0) ? c - 1 : 0;
    int cp = (c < S - 1) ? c + 1 : S - 1;
    float w_rt = (c < S - 1) ? 1.0f : 0.0f;   // quads in col c exist
    float w_lt = (c > 0)     ? 1.0f : 0.0f;   // quads in col c-1 exist

    const float* base = vrt + (size_t)b * n_verts * 3;

    // Load the (RPT+2)-row x 3-col register neighborhood. All indices are
    // compile-time constants after unroll -> stays in VGPRs (no scratch).
    // Border rows clamp; clamped contributions are zeroed by w_up/w_dn.
    f3 P[RPT + 2][3];
    #pragma unroll
    for (int i = 0; i < RPT + 2; ++i) {
        int rr = r0 - 1 + i;
        rr = (rr < 0) ? 0 : ((rr > S - 1) ? S - 1 : rr);
        P[i][0] = load_pt(base, S, rr, cm);
        P[i][1] = load_pt(base, S, rr, c);
        P[i][2] = load_pt(base, S, rr, cp);
    }

    float* ob = out + ((size_t)b * n_verts + (size_t)r0 * S + c) * 3;

    #pragma unroll
    for (int k = 0; k < RPT; ++k) {
        int r = r0 + k;
        if (r >= S) break;   // never taken for S % RPT == 0
        float w_dn = (r < S - 1) ? 1.0f : 0.0f;   // quads in row r exist
        float w_up = (r > 0)     ? 1.0f : 0.0f;   // quads in row r-1 exist

        f3 U  = P[k][1],     UR = P[k][2];
        f3 L  = P[k + 1][0], A  = P[k + 1][1], R = P[k + 1][2];
        f3 DL = P[k + 2][0], D  = P[k + 2][1];

        f3 s; s.x = 0.f; s.y = 0.f; s.z = 0.f;

        // Same face order / math as the verified round-2 kernel.
        accum_face(w_dn * w_rt, R - A,  D - A,  s);   // t1(r,c)
        accum_face(w_dn * w_lt, A - L,  DL - L, s);   // t1(r,c-1)
        accum_face(w_up * w_rt, UR - U, A - U,  s);   // t1(r-1,c)
        accum_face(w_dn * w_lt, D - A,  DL - A, s);   // t2(r,c-1)
        accum_face(w_up * w_lt, A - U,  L - U,  s);   // t2(r-1,c-1)
        accum_face(w_up * w_rt, R - UR, A - UR, s);   // t2(r-1,c)

        // Final normalize, matching reference: x / max(||x||, 1e-12).
        float nrm = sqrtf(s.x * s.x + s.y * s.y + s.z * s.z);
        float inv = 1.0f / fmaxf(nrm, 1e-12f);

        f3 o;
        o.x = s.x * inv;
        o.y = s.y * inv;
        o.z = s.z * inv;
        *reinterpret_cast<f3*>(ob + (size_t)k * S * 3) = o;
    }
}

extern "C" void kernel_launch(void* const* d_in, const int* in_sizes, int n_in,
                              void* d_out, int out_size, void* d_ws, size_t ws_size,
                              hipStream_t stream) {
    const float* vrt = (const float*)d_in[0];
    float*       out = (float*)d_out;

    // Derive S from F = 2*(S-1)^2, then BS from vrt size.
    int F = in_sizes[2] / 3;
    int S = 1 + (int)(sqrt((double)(F / 2)) + 0.5);
    int n_verts = S * S;
    int BS = in_sizes[0] / (3 * n_verts);

    dim3 grid((S + 255) / 256, (S + RPT - 1) / RPT, BS);
    vertex_normals_stencil<<<grid, 256, 0, stream>>>(vrt, out, S);
}